// Round 1
// baseline (706.284 us; speedup 1.0000x reference)
//
#include <hip/hip_runtime.h>
#include <cmath>

#define Bn   8
#define Cn   64
#define HWc  65536      // 256*256
#define HPc  246        // 256-11+1
#define HPWPc 60516     // 246*246
#define C1v  0.01f      // (0.01*10)^2
#define C2v  0.09f      // (0.03*10)^2

// 11-tap normalized gaussian, sigma=1.5 (matches np.exp in double, then f32 cast)
static __device__ __forceinline__ void gauss11(float* gw) {
    double gg[11]; double s = 0.0;
#pragma unroll
    for (int j = 0; j < 11; ++j) { double d = (double)(j - 5); gg[j] = exp(-(d * d) / 4.5); s += gg[j]; }
#pragma unroll
    for (int j = 0; j < 11; ++j) gw[j] = (float)(gg[j] / s);
}

static __device__ __forceinline__ float4 f4z() { return make_float4(0.f, 0.f, 0.f, 0.f); }
static __device__ __forceinline__ float4 f4scale(float g, const float4 v) {
    return make_float4(g * v.x, g * v.y, g * v.z, g * v.w);
}
static __device__ __forceinline__ void f4add(float4& a, const float4 v) {
    a.x += v.x; a.y += v.y; a.z += v.z; a.w += v.w;
}
static __device__ __forceinline__ void f4fma(float4& a, const float4 u, const float4 v) {
    a.x = fmaf(u.x, v.x, a.x); a.y = fmaf(u.y, v.y, a.y);
    a.z = fmaf(u.z, v.z, a.z); a.w = fmaf(u.w, v.w, a.w);
}

// horizontal 11-tap blur of 4 consecutive outputs from a vb row segment in LDS
static __device__ __forceinline__ void hblur4(const float* vb, int base, const float* gw, float* out4) {
    float w[14];
#pragma unroll
    for (int m = 0; m < 14; ++m) w[m] = vb[base + m];
#pragma unroll
    for (int j = 0; j < 4; ++j) {
        float s = 0.f;
#pragma unroll
        for (int k = 0; k < 11; ++k) s = fmaf(gw[k], w[j + k], s);
        out4[j] = s;
    }
}

// K1: channel max/mean/min (-> xcf planes [b][0..2]) + masked stats atomics
__global__ __launch_bounds__(256) void k1_stats(const float* __restrict__ x, const int* __restrict__ mask,
                                                float* __restrict__ xcf, float* __restrict__ stats) {
    const int b = blockIdx.y;
    const int p0 = blockIdx.x * 1024 + threadIdx.x * 4;
    const float4* xp = (const float4*)(x + (size_t)b * Cn * HWc) + (p0 >> 2);
    float4 v = xp[0];
    float4 vmax = v, vmin = v, vsum = v;
#pragma unroll 4
    for (int c = 1; c < Cn; ++c) {
        float4 u = xp[(size_t)c * (HWc / 4)];
        vmax.x = fmaxf(vmax.x, u.x); vmax.y = fmaxf(vmax.y, u.y);
        vmax.z = fmaxf(vmax.z, u.z); vmax.w = fmaxf(vmax.w, u.w);
        vmin.x = fminf(vmin.x, u.x); vmin.y = fminf(vmin.y, u.y);
        vmin.z = fminf(vmin.z, u.z); vmin.w = fminf(vmin.w, u.w);
        vsum.x += u.x; vsum.y += u.y; vsum.z += u.z; vsum.w += u.w;
    }
    float4 vmean = make_float4(vsum.x * (1.f / 64.f), vsum.y * (1.f / 64.f),
                               vsum.z * (1.f / 64.f), vsum.w * (1.f / 64.f));
    *(float4*)(xcf + (size_t)(b * 3 + 0) * HWc + p0) = vmax;
    *(float4*)(xcf + (size_t)(b * 3 + 1) * HWc + p0) = vmean;
    *(float4*)(xcf + (size_t)(b * 3 + 2) * HWc + p0) = vmin;
    int4 mv = *(const int4*)(mask + (size_t)b * HWc + p0);
    float m0 = (float)mv.x, m1 = (float)mv.y, m2 = (float)mv.z, m3 = (float)mv.w;
    float r[7];
    r[0] = m0 + m1 + m2 + m3;
    r[1] = vmax.x * m0 + vmax.y * m1 + vmax.z * m2 + vmax.w * m3;
    r[2] = vmean.x * m0 + vmean.y * m1 + vmean.z * m2 + vmean.w * m3;
    r[3] = vmin.x * m0 + vmin.y * m1 + vmin.z * m2 + vmin.w * m3;
    r[4] = vmax.x * vmax.x * m0 + vmax.y * vmax.y * m1 + vmax.z * vmax.z * m2 + vmax.w * vmax.w * m3;
    r[5] = vmean.x * vmean.x * m0 + vmean.y * vmean.y * m1 + vmean.z * vmean.z * m2 + vmean.w * vmean.w * m3;
    r[6] = vmin.x * vmin.x * m0 + vmin.y * vmin.y * m1 + vmin.z * vmin.z * m2 + vmin.w * vmin.w * m3;
#pragma unroll
    for (int k = 0; k < 7; ++k) {
        float vv = r[k];
#pragma unroll
        for (int off = 32; off > 0; off >>= 1) vv += __shfl_down(vv, off);
        if ((threadIdx.x & 63) == 0) atomicAdd(&stats[b * 8 + k], vv);
    }
}

// K3: xf = (xc - mean) * rsqrt(var) * m, in place in xcf
__global__ __launch_bounds__(256) void k3_xf(float* __restrict__ xcf, const int* __restrict__ mask,
                                             const float* __restrict__ stats) {
    const int b = blockIdx.z, i = blockIdx.y;
    const int p0 = blockIdx.x * 1024 + threadIdx.x * 4;
    const float* st = stats + b * 8;
    const float n = st[0];
    const float s1 = st[1 + i], s2 = st[4 + i];
    const float mean = s1 / n;
    const float var = (s2 - s1 * s1 / n) / (n - 1.0f);
    const float rstd = rsqrtf(var);
    float4* p = (float4*)(xcf + (size_t)(b * 3 + i) * HWc + p0);
    float4 v = *p;
    int4 mv = *(const int4*)(mask + (size_t)b * HWc + p0);
    v.x = (v.x - mean) * rstd * (float)mv.x;
    v.y = (v.y - mean) * rstd * (float)mv.y;
    v.z = (v.z - mean) * rstd * (float)mv.z;
    v.w = (v.w - mean) * rstd * (float)mv.w;
    *p = v;
}

// K4: mu_f = blur(xf), ef2 = blur(xf^2) for the 24 (b,i) planes. Tiled separable blur.
__global__ __launch_bounds__(256) void k4_blur3(const float* __restrict__ xf, float* __restrict__ muf,
                                                float* __restrict__ ef2g) {
    __shared__ __align__(16) float fin[42 * 44];
    __shared__ __align__(16) float vba[32 * 52];
    __shared__ __align__(16) float vbb[32 * 52];
    const int t = threadIdx.x;
    const int bi = blockIdx.z;
    const int y0 = blockIdx.y * 32, x0 = blockIdx.x * 32;
    float gw[11]; gauss11(gw);
    const float* src = xf + (size_t)bi * HWc;
    for (int q = t; q < 42 * 11; q += 256) {
        int row = q / 11, cg = q % 11;
        int gr = min(y0 + row, 255), gc = min(x0 + cg * 4, 252);
        *(float4*)&fin[row * 44 + cg * 4] = *(const float4*)(src + gr * 256 + gc);
    }
    __syncthreads();
    if (t < 88) {
        int rg = t / 11, cg = t % 11, colo = cg * 4;
        float4 aa[4], ab[4];
#pragma unroll
        for (int r = 0; r < 4; ++r) { aa[r] = f4z(); ab[r] = f4z(); }
#pragma unroll
        for (int k = 0; k < 14; ++k) {
            float4 v = *(const float4*)&fin[(4 * rg + k) * 44 + colo];
#pragma unroll
            for (int r = 0; r < 4; ++r) {
                int kk = k - r;
                if (kk >= 0 && kk <= 10) {
                    float4 tv = f4scale(gw[kk], v);
                    f4add(aa[r], tv);
                    f4fma(ab[r], tv, v);
                }
            }
        }
#pragma unroll
        for (int r = 0; r < 4; ++r) {
            int so = (4 * rg + r) * 52 + colo;
            *(float4*)&vba[so] = aa[r];
            *(float4*)&vbb[so] = ab[r];
        }
    }
    __syncthreads();
    {
        int erow = t >> 3, ecg = t & 7;
        int oyy = y0 + erow;
        int base = erow * 52 + ecg * 4;
        float o1[4], o2[4];
        hblur4(vba, base, gw, o1);
        hblur4(vbb, base, gw, o2);
        if (oyy < HPc) {
            size_t ob = (size_t)bi * HPWPc + (size_t)oyy * HPc;
#pragma unroll
            for (int j = 0; j < 4; ++j) {
                int ox = x0 + ecg * 4 + j;
                if (ox < HPc) { muf[ob + ox] = o1[j]; ef2g[ob + ox] = o2[j]; }
            }
        }
    }
}

// K5: per (b, 32x32 tile): persistent xf tiles in LDS, loop c over 64 channels.
// Vertical-first separable blur of {x, x^2, xf0*x, xf1*x, xf2*x}, horizontal pass
// fused with SSIM map eval and spatial-sum accumulation (atomics into ssum[b,i,c]).
__global__ __launch_bounds__(256, 2) void k5_main(const float* __restrict__ x, const float* __restrict__ xf,
                                                  const float* __restrict__ muf, const float* __restrict__ ef2g,
                                                  float* __restrict__ ssum) {
    __shared__ __align__(16) float xin[42 * 44];
    __shared__ __align__(16) float f0in[42 * 44];
    __shared__ __align__(16) float f1in[42 * 44];
    __shared__ __align__(16) float f2in[42 * 44];
    __shared__ __align__(16) float vbx[32 * 52];
    __shared__ __align__(16) float vbq[32 * 52];
    __shared__ __align__(16) float vb0[32 * 52];
    __shared__ __align__(16) float vb1a[32 * 52];
    __shared__ __align__(16) float vb2a[32 * 52];
    const int t = threadIdx.x;
    const int b = blockIdx.z;
    const int y0 = blockIdx.y * 32, x0 = blockIdx.x * 32;
    float gw[11]; gauss11(gw);
    // persistent xf tiles
    {
        const float* f0p = xf + (size_t)(b * 3 + 0) * HWc;
        const float* f1p = xf + (size_t)(b * 3 + 1) * HWc;
        const float* f2p = xf + (size_t)(b * 3 + 2) * HWc;
        for (int q = t; q < 42 * 11; q += 256) {
            int row = q / 11, cg = q % 11;
            int gr = min(y0 + row, 255), gc = min(x0 + cg * 4, 252);
            int go = gr * 256 + gc;
            int lo = row * 44 + cg * 4;
            *(float4*)&f0in[lo] = *(const float4*)(f0p + go);
            *(float4*)&f1in[lo] = *(const float4*)(f1p + go);
            *(float4*)&f2in[lo] = *(const float4*)(f2p + go);
        }
    }
    // per-thread eval constants (c-independent): mu1, mu1^2+C1, s1+C2, validity
    const int erow = t >> 3;   // 0..31 output row in tile
    const int ecg = t & 7;     // 0..7 -> 4 output cols
    const int oy = y0 + erow;
    float Am[3][4], A2C1[3][4], S1C2[3][4], validf[4];
#pragma unroll
    for (int j = 0; j < 4; ++j) {
        int ox = x0 + ecg * 4 + j;
        bool vld = (oy < HPc) && (ox < HPc);
        validf[j] = vld ? 1.0f : 0.0f;
#pragma unroll
        for (int i = 0; i < 3; ++i) {
            float mu1 = 0.f, e2 = 0.f;
            if (vld) {
                size_t o = (size_t)(b * 3 + i) * HPWPc + (size_t)oy * HPc + ox;
                mu1 = muf[o]; e2 = ef2g[o];
            }
            Am[i][j] = mu1;
            A2C1[i][j] = fmaf(mu1, mu1, C1v);
            S1C2[i][j] = (e2 - mu1 * mu1) + C2v;
        }
    }
    const float* xb = x + (size_t)b * Cn * HWc;
    for (int c = 0; c < Cn; ++c) {
        // stage x tile
        {
            const float* xp = xb + (size_t)c * HWc;
            for (int q = t; q < 42 * 11; q += 256) {
                int row = q / 11, cg = q % 11;
                int gr = min(y0 + row, 255), gc = min(x0 + cg * 4, 252);
                *(float4*)&xin[row * 44 + cg * 4] = *(const float4*)(xp + gr * 256 + gc);
            }
        }
        __syncthreads();
        // vertical pass: 88 threads, 4 rows x 4 cols each, 5 fields
        if (t < 88) {
            int rg = t / 11;        // 0..7
            int cg = t % 11;        // 0..10
            int colo = cg * 4;
            float4 ax[4], aq[4], a0[4], a1[4], a2[4];
#pragma unroll
            for (int r = 0; r < 4; ++r) { ax[r] = f4z(); aq[r] = f4z(); a0[r] = f4z(); a1[r] = f4z(); a2[r] = f4z(); }
#pragma unroll
            for (int k = 0; k < 14; ++k) {
                int ro = (4 * rg + k) * 44 + colo;
                float4 xv = *(const float4*)&xin[ro];
                float4 f0 = *(const float4*)&f0in[ro];
                float4 f1 = *(const float4*)&f1in[ro];
                float4 f2 = *(const float4*)&f2in[ro];
#pragma unroll
                for (int r = 0; r < 4; ++r) {
                    int kk = k - r;
                    if (kk >= 0 && kk <= 10) {
                        float4 tv = f4scale(gw[kk], xv);
                        f4add(ax[r], tv);
                        f4fma(aq[r], tv, xv);
                        f4fma(a0[r], tv, f0);
                        f4fma(a1[r], tv, f1);
                        f4fma(a2[r], tv, f2);
                    }
                }
            }
#pragma unroll
            for (int r = 0; r < 4; ++r) {
                int so = (4 * rg + r) * 52 + colo;
                *(float4*)&vbx[so] = ax[r];
                *(float4*)&vbq[so] = aq[r];
                *(float4*)&vb0[so] = a0[r];
                *(float4*)&vb1a[so] = a1[r];
                *(float4*)&vb2a[so] = a2[r];
            }
        }
        __syncthreads();
        // horizontal pass + ssim eval + per-c reduction
        {
            const int base = erow * 52 + ecg * 4;
            float mu2[4], bx2[4], bp0[4], bp1[4], bp2[4];
            hblur4(vbx, base, gw, mu2);
            hblur4(vbq, base, gw, bx2);
            hblur4(vb0, base, gw, bp0);
            hblur4(vb1a, base, gw, bp1);
            hblur4(vb2a, base, gw, bp2);
            float sa0 = 0.f, sa1 = 0.f, sa2 = 0.f;
#pragma unroll
            for (int j = 0; j < 4; ++j) {
                float m2 = mu2[j];
                float m2sq = m2 * m2;
                float s2 = bx2[j] - m2sq;
                {
                    float am = Am[0][j] * m2;
                    float num = fmaf(2.f, am, C1v) * fmaf(2.f, bp0[j] - am, C2v);
                    float den = (A2C1[0][j] + m2sq) * (S1C2[0][j] + s2);
                    sa0 += validf[j] * num * __builtin_amdgcn_rcpf(den);
                }
                {
                    float am = Am[1][j] * m2;
                    float num = fmaf(2.f, am, C1v) * fmaf(2.f, bp1[j] - am, C2v);
                    float den = (A2C1[1][j] + m2sq) * (S1C2[1][j] + s2);
                    sa1 += validf[j] * num * __builtin_amdgcn_rcpf(den);
                }
                {
                    float am = Am[2][j] * m2;
                    float num = fmaf(2.f, am, C1v) * fmaf(2.f, bp2[j] - am, C2v);
                    float den = (A2C1[2][j] + m2sq) * (S1C2[2][j] + s2);
                    sa2 += validf[j] * num * __builtin_amdgcn_rcpf(den);
                }
            }
#pragma unroll
            for (int off = 32; off > 0; off >>= 1) {
                sa0 += __shfl_down(sa0, off);
                sa1 += __shfl_down(sa1, off);
                sa2 += __shfl_down(sa2, off);
            }
            if ((t & 63) == 0) {
                atomicAdd(&ssum[(b * 3 + 0) * 64 + c], sa0);
                atomicAdd(&ssum[(b * 3 + 1) * 64 + c], sa1);
                atomicAdd(&ssum[(b * 3 + 2) * 64 + c], sa2);
            }
        }
        // next iteration's __syncthreads() after x staging protects vb/xin reuse
    }
}

// K6: normalize ssim sums -> ssim_info output; conv3 over the C dim + MLP head -> h output
__global__ __launch_bounds__(512) void k6_head(const float* __restrict__ ssum, const float* __restrict__ cw,
                                               const float* __restrict__ w1, const float* __restrict__ b1,
                                               const float* __restrict__ w2, const float* __restrict__ b2,
                                               float* __restrict__ out) {
    __shared__ float si[1536];
    __shared__ float h0[512];
    __shared__ float h1[512];
    const int t = threadIdx.x;
    const float inv = 1.0f / (float)HPWPc;
    for (int idx = t; idx < 1536; idx += 512) {
        float v = ssum[idx] * inv;
        si[idx] = v;
        out[512 + idx] = v;
    }
    __syncthreads();
    const int b = t >> 6, y = t & 63;
    float acc = 0.f;
#pragma unroll
    for (int i = 0; i < 3; ++i) {
#pragma unroll
        for (int kh = 0; kh < 3; ++kh) {
            int yy = y + kh - 1;
            if (yy >= 0 && yy < 64) acc = fmaf(si[(b * 3 + i) * 64 + yy], cw[i * 3 + kh], acc);
        }
    }
    h0[t] = fmaxf(acc, 0.f);
    __syncthreads();
    float a1 = b1[y];
    for (int c = 0; c < 64; ++c) a1 = fmaf(h0[(b << 6) + c], w1[(y << 6) + c], a1);
    h1[t] = fmaxf(a1, 0.f);
    __syncthreads();
    float a2 = b2[y];
    for (int c = 0; c < 64; ++c) a2 = fmaf(h1[(b << 6) + c], w2[(y << 6) + c], a2);
    out[t] = 1.f / (1.f + expf(-a2));
}

extern "C" void kernel_launch(void* const* d_in, const int* in_sizes, int n_in,
                              void* d_out, int out_size, void* d_ws, size_t ws_size,
                              hipStream_t stream) {
    const float* x      = (const float*)d_in[0];
    const int*   mask   = (const int*)d_in[1];
    const float* conv_w = (const float*)d_in[2];
    const float* w1     = (const float*)d_in[3];
    const float* b1     = (const float*)d_in[4];
    const float* w2     = (const float*)d_in[5];
    const float* b2     = (const float*)d_in[6];
    float* out = (float*)d_out;

    float* wsf   = (float*)d_ws;
    float* stats = wsf;                       // 64 floats (8 b x 8 slots)
    float* ssum  = wsf + 64;                  // 1536 floats
    float* xcf   = wsf + 1600;                // 8*3*65536 (xc, then xf in place)
    float* muf   = xcf + (size_t)Bn * 3 * HWc;      // 8*3*60516
    float* ef2   = muf + (size_t)Bn * 3 * HPWPc;    // 8*3*60516
    // total ws use: ~17.9 MB

    hipMemsetAsync(d_ws, 0, 6400, stream);  // stats + ssum accumulators

    k1_stats<<<dim3(64, 8), 256, 0, stream>>>(x, mask, xcf, stats);
    k3_xf<<<dim3(64, 3, 8), 256, 0, stream>>>(xcf, mask, stats);
    k4_blur3<<<dim3(8, 8, 24), 256, 0, stream>>>(xcf, muf, ef2);
    k5_main<<<dim3(8, 8, 8), 256, 0, stream>>>(x, xcf, muf, ef2, ssum);
    k6_head<<<1, 512, 0, stream>>>(ssum, conv_w, w1, b1, w2, b2, out);
}